// Round 1
// baseline (229.958 us; speedup 1.0000x reference)
//
#include <hip/hip_runtime.h>
#include <hip/hip_bf16.h>

#define NB 8
#define NQ 16
#define NP 4096
#define NHID 4096
#define NHEADS 32
#define NKVH 8
#define NG 4
#define ND 128
#define NM 128          // NB*NQ
#define NSEQ 4112       // NP+NQ
#define N_QKV 6144
#define SPLITK1 4
#define SPLITK3 8
#define NS_ATT 8

typedef __attribute__((ext_vector_type(8))) short bf16x8;
typedef __attribute__((ext_vector_type(4))) float f32x4;

__device__ __forceinline__ unsigned short f2bf(float f) {
  unsigned int u = __float_as_uint(f);
  u = (u + 0x7FFFu + ((u >> 16) & 1u)) >> 16;
  return (unsigned short)u;
}

// ---------------- hidden fp32 -> bf16 ----------------
__global__ __launch_bounds__(256) void k_cvt(const float* __restrict__ x,
                                             unsigned short* __restrict__ y, int n4) {
  int i = blockIdx.x * 256 + threadIdx.x;
  if (i >= n4) return;
  float4 v = ((const float4*)x)[i];
  ushort4 o;
  o.x = f2bf(v.x); o.y = f2bf(v.y); o.z = f2bf(v.z); o.w = f2bf(v.w);
  ((ushort4*)y)[i] = o;
}

// ---------------- split-K MFMA GEMM: A[128][lda] bf16 @ W[K][N] fp32 -> partials ----------------
__global__ __launch_bounds__(256) void k_gemm(
    const unsigned short* __restrict__ A, int lda,
    const float* __restrict__ W0, const float* __restrict__ W1, const float* __restrict__ W2,
    int nw0, int nw1, int N, int KS,
    float* __restrict__ part) {
  __shared__ unsigned short Blds[128][40];   // [n][k] transposed tile, pad stride 40
  int n0 = blockIdx.x * 128;
  int k0 = blockIdx.y * KS;
  const float* Wp; int ldw, ncol;
  if (n0 < nw0)      { Wp = W0; ldw = nw0;       ncol = n0; }
  else if (n0 < nw1) { Wp = W1; ldw = nw1 - nw0; ncol = n0 - nw0; }
  else               { Wp = W2; ldw = N - nw1;   ncol = n0 - nw1; }
  int tid = threadIdx.x, lane = tid & 63, wid = tid >> 6;
  int r16 = lane & 15, hi = lane >> 4;
  int wr = wid >> 1, wc = wid & 1;
  f32x4 acc[4][4];
#pragma unroll
  for (int i = 0; i < 4; ++i)
#pragma unroll
    for (int j = 0; j < 4; ++j) acc[i][j] = {0.f, 0.f, 0.f, 0.f};
  int krow = tid >> 5, n4 = tid & 31;
  for (int kk = 0; kk < KS; kk += 32) {
#pragma unroll
    for (int it = 0; it < 4; ++it) {
      int k = krow + it * 8;
      float4 w = *(const float4*)&Wp[(size_t)(k0 + kk + k) * ldw + ncol + n4 * 4];
      Blds[n4 * 4 + 0][k] = f2bf(w.x);
      Blds[n4 * 4 + 1][k] = f2bf(w.y);
      Blds[n4 * 4 + 2][k] = f2bf(w.z);
      Blds[n4 * 4 + 3][k] = f2bf(w.w);
    }
    __syncthreads();
    bf16x8 af[4], bfr[4];
#pragma unroll
    for (int rt = 0; rt < 4; ++rt)
      af[rt] = *(const bf16x8*)&A[(size_t)(wr * 64 + rt * 16 + r16) * lda + k0 + kk + hi * 8];
#pragma unroll
    for (int ct = 0; ct < 4; ++ct)
      bfr[ct] = *(const bf16x8*)&Blds[wc * 64 + ct * 16 + r16][hi * 8];
#pragma unroll
    for (int rt = 0; rt < 4; ++rt)
#pragma unroll
      for (int ct = 0; ct < 4; ++ct)
        acc[rt][ct] = __builtin_amdgcn_mfma_f32_16x16x32_bf16(af[rt], bfr[ct], acc[rt][ct], 0, 0, 0);
    __syncthreads();
  }
  float* po = part + (size_t)blockIdx.y * NM * N;
#pragma unroll
  for (int rt = 0; rt < 4; ++rt)
#pragma unroll
    for (int ct = 0; ct < 4; ++ct)
#pragma unroll
      for (int r = 0; r < 4; ++r) {
        int m = wr * 64 + rt * 16 + hi * 4 + r;
        int n = n0 + wc * 64 + ct * 16 + r16;
        po[(size_t)m * N + n] = acc[rt][ct][r];
      }
}

// ---------------- reduce QKV partials + RoPE + scale-fold -> bf16 q/k/v ----------------
__global__ __launch_bounds__(256) void k_rope(
    const float* __restrict__ part, const void* __restrict__ posv,
    unsigned short* __restrict__ qb, unsigned short* __restrict__ kb,
    unsigned short* __restrict__ vb) {
  int t = blockIdx.x * 256 + threadIdx.x;   // 128*48*64 total
  int d = t & 63;
  int rest = t >> 6;
  int h = rest % 48;
  int m = rest / 48;
  if (m >= NM) return;
  const int* p32 = (const int*)posv;
  const long long* p64 = (const long long*)posv;
  bool is64 = (p64[0] == (long long)p32[0]);   // int64 layout has zero upper half
  int pos = is64 ? (int)p64[m] : p32[m];
  int b = m >> 4, q = m & 15;

  int c1, c2;
  if (h < 32)      { c1 = h * ND + d; }
  else if (h < 40) { c1 = NHID + (h - 32) * ND + d; }
  else             { c1 = NHID + 1024 + (h - 40) * ND + d; }
  c2 = c1 + 64;
  float x1 = 0.f, x2 = 0.f;
#pragma unroll
  for (int c = 0; c < SPLITK1; ++c) {
    x1 += part[((size_t)c * NM + m) * N_QKV + c1];
    x2 += part[((size_t)c * NM + m) * N_QKV + c2];
  }
  if (h < 40) {  // q or k: RoPE pair (d, d+64)
    float invf = __expf(-(float)d * 0.14391156831212787f);  // ln(10000)/64
    float th = (float)pos * invf;
    float cs = cosf(th), sn = sinf(th);
    float o1 = x1 * cs - x2 * sn;
    float o2 = x2 * cs + x1 * sn;
    if (h < 32) {
      o1 *= 0.08838834764831845f;  // 1/sqrt(128)
      o2 *= 0.08838834764831845f;
      int kv = h >> 2, g = h & 3;
      size_t base = ((((size_t)b * NKVH + kv) * NG + g) * NQ + q) * ND;
      qb[base + d] = f2bf(o1);
      qb[base + d + 64] = f2bf(o2);
    } else {
      int kvh = h - 32;
      size_t base = (((size_t)b * NKVH + kvh) * NQ + q) * ND;
      kb[base + d] = f2bf(o1);
      kb[base + d + 64] = f2bf(o2);
    }
  } else {
    int kvh = h - 40;
    size_t base = (((size_t)b * NKVH + kvh) * NQ + q) * ND;
    vb[base + d] = f2bf(x1);
    vb[base + d + 64] = f2bf(x2);
  }
}

// ---------------- flash attention with S-splits ----------------
__global__ __launch_bounds__(256) void k_attn(
    const unsigned short* __restrict__ qb, const unsigned short* __restrict__ kb,
    const unsigned short* __restrict__ vb, const float* __restrict__ pastK,
    const float* __restrict__ pastV, const float* __restrict__ bias,
    float* __restrict__ pout, float* __restrict__ pml) {
  __shared__ unsigned short Klds[64][136];       // [s][d], stride 136 (272B, 16B-aligned rows)
  __shared__ unsigned short Vlds[64 * 136];      // [s][d] with XOR swizzle on d within row
  __shared__ unsigned short Plds[4][16][72];     // per-wave P tile [q][j]
  int bkv = blockIdx.x;
  int split = blockIdx.y;
  int b = bkv >> 3, kv = bkv & 7;
  int tid = threadIdx.x, lane = tid & 63, wid = tid >> 6;
  int r16 = lane & 15, hi = lane >> 4;

  const unsigned short* qbase = qb + ((((size_t)b * NKVH + kv) * NG + wid) * NQ) * ND;
  bf16x8 qf[4];
#pragma unroll
  for (int kd = 0; kd < 4; ++kd)
    qf[kd] = *(const bf16x8*)&qbase[r16 * ND + kd * 32 + hi * 8];

  float m_run[4], l_run[4];
  f32x4 oacc[8];
#pragma unroll
  for (int r = 0; r < 4; ++r) { m_run[r] = -1e30f; l_run[r] = 0.f; }
#pragma unroll
  for (int dt = 0; dt < 8; ++dt) oacc[dt] = {0.f, 0.f, 0.f, 0.f};

  int s0 = split * 512;
  int nsub = (split == NS_ATT - 1) ? 9 : 8;
  const float* Kg = pastK + ((size_t)(b * NKVH + kv) * NP + s0) * ND;
  const float* Vg = pastV + ((size_t)(b * NKVH + kv) * NP + s0) * ND;

  for (int sub = 0; sub < nsub; ++sub) {
    bool tail = (sub == 8);
    if (!tail) {
      int d4 = tid & 31;
      int sr = tid >> 5;
#pragma unroll
      for (int it = 0; it < 8; ++it) {
        int s = sr + it * 8;
        float4 kw = *(const float4*)&Kg[(size_t)(sub * 64 + s) * ND + d4 * 4];
        ushort4 k4;
        k4.x = f2bf(kw.x); k4.y = f2bf(kw.y); k4.z = f2bf(kw.z); k4.w = f2bf(kw.w);
        *(ushort4*)&Klds[s][d4 * 4] = k4;
        float4 vw = *(const float4*)&Vg[(size_t)(sub * 64 + s) * ND + d4 * 4];
        ushort4 v4;
        v4.x = f2bf(vw.x); v4.y = f2bf(vw.y); v4.z = f2bf(vw.z); v4.w = f2bf(vw.w);
        *(ushort4*)((char*)Vlds + s * 272 + ((d4 * 8) ^ (((s >> 3) & 3) << 5))) = v4;
      }
    } else {
      int s = tid >> 4, d8 = tid & 15;
      const unsigned short* Kn = kb + (((size_t)b * NKVH + kv) * NQ) * ND;
      const unsigned short* Vn = vb + (((size_t)b * NKVH + kv) * NQ) * ND;
      bf16x8 kn = *(const bf16x8*)&Kn[s * ND + d8 * 8];
      *(bf16x8*)&Klds[s][d8 * 8] = kn;
      bf16x8 vn = *(const bf16x8*)&Vn[s * ND + d8 * 8];
      *(bf16x8*)((char*)Vlds + s * 272 + ((d8 * 16) ^ (((s >> 3) & 3) << 5))) = vn;
    }
    __syncthreads();

    // scores = q @ K^T  (rows q = hi*4+r, cols j = ct*16+r16)
    f32x4 sc[4];
#pragma unroll
    for (int ct = 0; ct < 4; ++ct) {
      f32x4 a = {0.f, 0.f, 0.f, 0.f};
#pragma unroll
      for (int kd = 0; kd < 4; ++kd) {
        bf16x8 kf = *(const bf16x8*)&Klds[ct * 16 + r16][kd * 32 + hi * 8];
        a = __builtin_amdgcn_mfma_f32_16x16x32_bf16(qf[kd], kf, a, 0, 0, 0);
      }
      sc[ct] = a;
    }
    if (!tail) {
#pragma unroll
      for (int ct = 0; ct < 4; ++ct)
#pragma unroll
        for (int r = 0; r < 4; ++r) {
          int sg = s0 + sub * 64 + ct * 16 + r16;
          sc[ct][r] += bias[(size_t)(b * NQ + hi * 4 + r) * NSEQ + sg];
        }
    } else {
#pragma unroll
      for (int ct = 0; ct < 4; ++ct)
#pragma unroll
        for (int r = 0; r < 4; ++r) {
          int j = ct * 16 + r16;
          if (j < NQ)
            sc[ct][r] += bias[(size_t)(b * NQ + hi * 4 + r) * NSEQ + NP + j];
          else
            sc[ct][r] = -1e30f;
        }
    }
    // online softmax (row stats live in lanes sharing hi; reduce over r16 via shfl)
    float mnew[4], fac[4], rs[4];
#pragma unroll
    for (int r = 0; r < 4; ++r) {
      float v = fmaxf(fmaxf(sc[0][r], sc[1][r]), fmaxf(sc[2][r], sc[3][r]));
      v = fmaxf(v, __shfl_xor(v, 1));
      v = fmaxf(v, __shfl_xor(v, 2));
      v = fmaxf(v, __shfl_xor(v, 4));
      v = fmaxf(v, __shfl_xor(v, 8));
      mnew[r] = fmaxf(m_run[r], v);
      fac[r] = __expf(m_run[r] - mnew[r]);
      m_run[r] = mnew[r];
      rs[r] = 0.f;
    }
#pragma unroll
    for (int ct = 0; ct < 4; ++ct)
#pragma unroll
      for (int r = 0; r < 4; ++r) {
        float p = __expf(sc[ct][r] - mnew[r]);
        rs[r] += p;
        Plds[wid][hi * 4 + r][ct * 16 + r16] = f2bf(p);
      }
#pragma unroll
    for (int r = 0; r < 4; ++r) {
      float s = rs[r];
      s += __shfl_xor(s, 1);
      s += __shfl_xor(s, 2);
      s += __shfl_xor(s, 4);
      s += __shfl_xor(s, 8);
      l_run[r] = l_run[r] * fac[r] + s;
    }
#pragma unroll
    for (int dt = 0; dt < 8; ++dt)
#pragma unroll
      for (int r = 0; r < 4; ++r) oacc[dt][r] *= fac[r];
    // PV: out[q][d] += P[q][j] * V[j][d]
#pragma unroll
    for (int kt = 0; kt < 2; ++kt) {
      bf16x8 pa = *(const bf16x8*)&Plds[wid][r16][kt * 32 + hi * 8];
#pragma unroll
      for (int dt = 0; dt < 8; ++dt) {
        bf16x8 vf;
#pragma unroll
        for (int e = 0; e < 8; ++e) {
          int j = kt * 32 + hi * 8 + e;
          int d2 = (dt * 16 + r16) * 2;
          vf[e] = *(const short*)((const char*)Vlds + j * 272 + (d2 ^ (((j >> 3) & 3) << 5)));
        }
        oacc[dt] = __builtin_amdgcn_mfma_f32_16x16x32_bf16(pa, vf, oacc[dt], 0, 0, 0);
      }
    }
    __syncthreads();
  }
  size_t rowbase = ((size_t)(b * NKVH + kv) * NG + wid) * NQ;
  float* po = pout + ((size_t)split * (NB * NKVH * NG * NQ) + rowbase) * ND;
#pragma unroll
  for (int dt = 0; dt < 8; ++dt)
#pragma unroll
    for (int r = 0; r < 4; ++r)
      po[(size_t)(hi * 4 + r) * ND + dt * 16 + r16] = oacc[dt][r];
  if (r16 == 0) {
#pragma unroll
    for (int r = 0; r < 4; ++r) {
      size_t idx = ((size_t)split * (NB * NKVH * NG * NQ) + rowbase + hi * 4 + r) * 2;
      pml[idx] = m_run[r];
      pml[idx + 1] = l_run[r];
    }
  }
}

// ---------------- combine split partials -> bf16 A for the Wo GEMM ----------------
__global__ __launch_bounds__(256) void k_combine(
    const float* __restrict__ pout, const float* __restrict__ pml,
    unsigned short* __restrict__ Aatt) {
  const int NROW = NB * NKVH * NG * NQ;  // 8192
  int row = blockIdx.x * 2 + (threadIdx.x >> 7);
  int d = threadIdx.x & 127;
  float mv[NS_ATT], lv[NS_ATT];
  float M = -1e30f;
#pragma unroll
  for (int c = 0; c < NS_ATT; ++c) {
    mv[c] = pml[((size_t)c * NROW + row) * 2];
    lv[c] = pml[((size_t)c * NROW + row) * 2 + 1];
    M = fmaxf(M, mv[c]);
  }
  float L = 0.f, acc = 0.f;
#pragma unroll
  for (int c = 0; c < NS_ATT; ++c) {
    float w = __expf(mv[c] - M);
    L += lv[c] * w;
    acc += pout[((size_t)c * NROW + row) * ND + d] * w;
  }
  float o = acc / L;
  int q = row & 15, g = (row >> 4) & 3, kvh = (row >> 6) & 7, b = row >> 9;
  Aatt[(size_t)(b * NQ + q) * NHID + (kvh * NG + g) * ND + d] = f2bf(o);
}

// ---------------- reduce Wo partials -> d_out ----------------
__global__ __launch_bounds__(256) void k_red(const float* __restrict__ part,
                                             float* __restrict__ out) {
  int i = blockIdx.x * 256 + threadIdx.x;  // < 128*4096
  float s = 0.f;
#pragma unroll
  for (int c = 0; c < SPLITK3; ++c) s += part[(size_t)c * (NM * NHID) + i];
  out[i] = s;
}

extern "C" void kernel_launch(void* const* d_in, const int* in_sizes, int n_in,
                              void* d_out, int out_size, void* d_ws, size_t ws_size,
                              hipStream_t stream) {
  const float* hidden = (const float*)d_in[0];
  const void* pos = d_in[1];
  const float* pastK = (const float*)d_in[2];
  const float* pastV = (const float*)d_in[3];
  const float* bias = (const float*)d_in[4];
  const float* Wq = (const float*)d_in[5];
  const float* Wk = (const float*)d_in[6];
  const float* Wv = (const float*)d_in[7];
  const float* Wo = (const float*)d_in[8];
  float* out = (float*)d_out;

  char* ws = (char*)d_ws;
  size_t off = 0;
  auto alloc = [&](size_t bytes) {
    char* p = ws + off;
    off += (bytes + 255) & ~(size_t)255;
    return p;
  };
  unsigned short* hb   = (unsigned short*)alloc((size_t)NM * NHID * 2);
  unsigned short* qb   = (unsigned short*)alloc((size_t)NB * NKVH * NG * NQ * ND * 2);
  unsigned short* kb   = (unsigned short*)alloc((size_t)NB * NKVH * NQ * ND * 2);
  unsigned short* vb   = (unsigned short*)alloc((size_t)NB * NKVH * NQ * ND * 2);
  unsigned short* Aatt = (unsigned short*)alloc((size_t)NM * NHID * 2);
  float* pml  = (float*)alloc((size_t)NS_ATT * 8192 * 2 * 4);
  float* pout = (float*)alloc((size_t)NS_ATT * 8192 * ND * 4);
  float* part = (float*)alloc((size_t)SPLITK3 * NM * NHID * 4);  // 16.8 MB >= QKV partials too

  k_cvt<<<512, 256, 0, stream>>>(hidden, hb, NM * NHID / 4);
  k_gemm<<<dim3(48, SPLITK1), 256, 0, stream>>>(hb, NHID, Wq, Wk, Wv, 4096, 5120,
                                                N_QKV, NHID / SPLITK1, part);
  k_rope<<<1536, 256, 0, stream>>>(part, pos, qb, kb, vb);
  k_attn<<<dim3(64, NS_ATT), 256, 0, stream>>>(qb, kb, vb, pastK, pastV, bias, pout, pml);
  k_combine<<<4096, 256, 0, stream>>>(pout, pml, Aatt);
  k_gemm<<<dim3(32, SPLITK3), 256, 0, stream>>>(Aatt, NHID, Wo, Wo, Wo, 4096, 8192,
                                                NHID, NHID / SPLITK3, part);
  k_red<<<2048, 256, 0, stream>>>(part, out);
}